// Round 1
// 195.663 us; speedup vs baseline: 1.0584x; 1.0584x over previous
//
#include <hip/hip_runtime.h>

#define N_NODES 50000
#define N_EDGES 800000
#define N_GRAPHS 256
#define F 64
#define NBUCK 196          // ceil(50000/256) coarse buckets (dst>>8)
#define CAP 5120           // per-bucket capacity incl. 4-align padding
#define P3_TILE 2048
#define P3_GRID ((N_EDGES + P3_TILE - 1) / P3_TILE)
#define BCAP 6144
#define ZOFF (N_NODES * 128) // byte offset of the zero row in Hn

// ---- bf16 helpers (RTN), all math stays f32 ----
__device__ __forceinline__ unsigned short f2bf(float f) {
    union { float f; unsigned u; } c; c.f = f;
    unsigned u = c.u + 0x7FFFu + ((c.u >> 16) & 1u);
    return (unsigned short)(u >> 16);
}
__device__ __forceinline__ unsigned pack2bf(float lo, float hi) {
    return (unsigned)f2bf(lo) | ((unsigned)f2bf(hi) << 16);
}
__device__ __forceinline__ float bfl(unsigned u) {
    union { unsigned u; float f; } c; c.u = u << 16; return c.f;
}
__device__ __forceinline__ float bfh(unsigned u) {
    union { unsigned u; float f; } c; c.u = u & 0xFFFF0000u; return c.f;
}

// ---------------- P1: partition edges into fixed-capacity buckets ----------------
__global__ __launch_bounds__(256) void partition_edges(const int* __restrict__ src,
                                                       const int* __restrict__ dst,
                                                       int* __restrict__ bcur,
                                                       unsigned int* __restrict__ bpair) {
    __shared__ int bh[NBUCK], bloc[NBUCK], bpos[NBUCK];
    int t = threadIdx.x;
    int lo = blockIdx.x * P3_TILE;
    int hi = min(lo + P3_TILE, N_EDGES);
    for (int i = t; i < NBUCK; i += 256) { bh[i] = 0; bpos[i] = 0; }
    __syncthreads();
    for (int e = lo + t; e < hi; e += 256) atomicAdd(&bh[dst[e] >> 8], 1);
    __syncthreads();
    for (int i = t; i < NBUCK; i += 256)
        bloc[i] = bh[i] ? atomicAdd(&bcur[i], bh[i]) : 0;
    __syncthreads();
    for (int e = lo + t; e < hi; e += 256) {
        int d = dst[e];
        int b = d >> 8;
        int r = atomicAdd(&bpos[b], 1);
        bpair[(size_t)b * CAP + bloc[b] + r] = ((unsigned)src[e] << 8) | (unsigned)(d & 255);
    }
}

// ---------------- P2: per-bucket counting sort -> 4-aligned padded CSR ----------------
// eidx runs are padded to a multiple of 4 with ZOFF (zero-row) sentinels.
// Also zeroes the zero row (row N) of BOTH bf16 Hn buffers.
__global__ __launch_bounds__(256) void bucket_sort(const unsigned int* __restrict__ bpair,
                                                   const int* __restrict__ bcur,
                                                   int* __restrict__ eidx,
                                                   int* __restrict__ rbeg,
                                                   int* __restrict__ rend,
                                                   float* __restrict__ dinv,
                                                   unsigned short* __restrict__ Abf,
                                                   unsigned short* __restrict__ Bbf) {
    __shared__ int cnt[256], s[256], pos[256];
    __shared__ int lout[BCAP];
    int b = blockIdx.x, t = threadIdx.x;
    int base = b * CAP;
    int sz = bcur[b];

    if (b == 0 && t < 8) {
        ((uint4*)Abf)[(size_t)N_NODES * 8 + t] = make_uint4(0u, 0u, 0u, 0u);
        ((uint4*)Bbf)[(size_t)N_NODES * 8 + t] = make_uint4(0u, 0u, 0u, 0u);
    }

    cnt[t] = 0;
    __syncthreads();
    for (int i = t; i < sz; i += 256) atomicAdd(&cnt[bpair[base + i] & 255], 1);
    __syncthreads();
    int v = cnt[t];
    int pv = (v + 3) & ~3;          // padded to multiple of 4
    s[t] = pv;
    __syncthreads();
    for (int off = 1; off < 256; off <<= 1) {
        int u = (t >= off) ? s[t - off] : 0;
        __syncthreads();
        s[t] += u;
        __syncthreads();
    }
    int excl = s[t] - pv;            // padded exclusive prefix
    pos[t] = excl;
    int node = b * 256 + t;
    if (node < N_NODES) {
        rbeg[node] = base + excl;
        rend[node] = base + excl + pv;                 // padded end (loop bound)
        dinv[node] = 1.0f / sqrtf((float)v + 1.0f);    // actual degree +1 self-loop
    }
    int padtot = s[255];             // total padded size of this bucket
    __syncthreads();

    // scatter actual edges
    for (int i = t; i < sz; i += 256) {
        unsigned p = bpair[base + i];
        int r = atomicAdd(&pos[p & 255], 1);
        lout[r] = (int)((p >> 8) << 7);   // src byte offset (src*128, bf16 row)
    }
    __syncthreads();
    // fill pad slots with zero-row sentinel (each thread pads its own node run)
    for (int j = v; j < pv; j++) lout[excl + j] = ZOFF;
    __syncthreads();
    for (int i = t; i < padtot; i += 256) eidx[base + i] = lout[i];
}

// ---------------- GEMM + dinv fold: Hn[i,:] = bf16( (X[i,:] @ W) * dinv[i] ) ----------------
// Only used for layer 1 (f32 input x); layers 2/3 GEMMs are fused into the gathers.
#define XSTRIDE 17
__global__ __launch_bounds__(256) void gemm64_f32(const float* __restrict__ X,
                                                  const float* __restrict__ W,
                                                  const float* __restrict__ dinv,
                                                  unsigned short* __restrict__ Hn, int n) {
    __shared__ float4 sW[64 * 16];
    __shared__ float4 sX[128 * XSTRIDE];
    int tid = threadIdx.x;
    int base = blockIdx.x * 128;

    const float4* W4 = (const float4*)W;
    for (int i = tid; i < 64 * 16; i += 256) sW[i] = W4[i];
    {
        const float4* X4 = (const float4*)X;
        for (int i = tid; i < 128 * 16; i += 256) {
            int r = i >> 4, kg = i & 15;
            int node = base + r;
            sX[r * XSTRIDE + kg] = (node < n) ? X4[(size_t)node * 16 + kg]
                                              : make_float4(0.f, 0.f, 0.f, 0.f);
        }
    }
    __syncthreads();

    int fg = tid & 15;
    int ng = tid >> 4;
    float4 acc[8];
#pragma unroll
    for (int ii = 0; ii < 8; ii++) acc[ii] = make_float4(0.f, 0.f, 0.f, 0.f);

    for (int kg = 0; kg < 16; kg++) {
        float4 xv[8];
#pragma unroll
        for (int ii = 0; ii < 8; ii++) xv[ii] = sX[(ng + 16 * ii) * XSTRIDE + kg];
#pragma unroll
        for (int kk = 0; kk < 4; kk++) {
            float4 wv = sW[(4 * kg + kk) * 16 + fg];
#pragma unroll
            for (int ii = 0; ii < 8; ii++) {
                float xs = (kk == 0) ? xv[ii].x : (kk == 1) ? xv[ii].y
                         : (kk == 2) ? xv[ii].z : xv[ii].w;
                acc[ii].x += wv.x * xs;
                acc[ii].y += wv.y * xs;
                acc[ii].z += wv.z * xs;
                acc[ii].w += wv.w * xs;
            }
        }
    }

    ushort4* H4 = (ushort4*)Hn;
#pragma unroll
    for (int ii = 0; ii < 8; ii++) {
        int node = base + ng + 16 * ii;
        if (node < n) {
            float d = dinv[node];
            float4 o = acc[ii];
            ushort4 u;
            u.x = f2bf(o.x * d); u.y = f2bf(o.y * d);
            u.z = f2bf(o.z * d); u.w = f2bf(o.w * d);
            H4[(size_t)node * 16 + fg] = u;
        }
    }
}

// ---------------- fused gather + next-layer GEMM (layers 1->2, 2->3) ----------------
// Per wave: 8 nodes, 8 lanes/node (8 feats/lane). Gather+bias+ReLU gives h (f32, no
// bf16 round-trip), then y = h @ W via ds_bpermute broadcast + 16KB LDS-resident W,
// then Hout[node] = bf16(y * dinv[node]). Eliminates the standalone GEMM kernel and
// the Bbf intermediate; matmul VALU work hides in the gather's memory-latency stalls.
__global__ __launch_bounds__(256) void gather_gemm(const int* __restrict__ rbeg,
                                                   const int* __restrict__ rend,
                                                   const int* __restrict__ eidx,
                                                   const float* __restrict__ dinv,
                                                   const unsigned short* __restrict__ Hin,
                                                   const float* __restrict__ bias,
                                                   const float* __restrict__ W,
                                                   unsigned short* __restrict__ Hout, int n) {
    __shared__ float4 sW[64 * 16];
    const float4* W4 = (const float4*)W;
    for (int i = threadIdx.x; i < 64 * 16; i += 256) sW[i] = W4[i];
    __syncthreads();

    int wv = (blockIdx.x * blockDim.x + threadIdx.x) >> 6;
    if (wv * 8 >= n) return;          // whole-wave guard (n % 8 == 0)
    int lane = threadIdx.x & 63;
    int ns = lane >> 3, f = lane & 7;
    int node = wv * 8 + ns;
    int beg = rbeg[node];
    int end = rend[node];
    const char* Hb = (const char*)Hin;

    float a0 = 0.f, a1 = 0.f, a2 = 0.f, a3 = 0.f;
    float a4 = 0.f, a5 = 0.f, a6 = 0.f, a7 = 0.f;
    for (int k = beg; k < end; k += 4) {
        int4 o = *(const int4*)(eidx + k);
        uint4 p = *(const uint4*)(Hb + o.x + f * 16);
        uint4 q = *(const uint4*)(Hb + o.y + f * 16);
        uint4 r = *(const uint4*)(Hb + o.z + f * 16);
        uint4 w = *(const uint4*)(Hb + o.w + f * 16);
        a0 += (bfl(p.x) + bfl(q.x)) + (bfl(r.x) + bfl(w.x));
        a1 += (bfh(p.x) + bfh(q.x)) + (bfh(r.x) + bfh(w.x));
        a2 += (bfl(p.y) + bfl(q.y)) + (bfl(r.y) + bfl(w.y));
        a3 += (bfh(p.y) + bfh(q.y)) + (bfh(r.y) + bfh(w.y));
        a4 += (bfl(p.z) + bfl(q.z)) + (bfl(r.z) + bfl(w.z));
        a5 += (bfh(p.z) + bfh(q.z)) + (bfh(r.z) + bfh(w.z));
        a6 += (bfl(p.w) + bfl(q.w)) + (bfl(r.w) + bfl(w.w));
        a7 += (bfh(p.w) + bfh(q.w)) + (bfh(r.w) + bfh(w.w));
    }

    float di = dinv[node];
    uint4 hs = *(const uint4*)(Hb + (size_t)node * 128 + f * 16);
    float4 bb0 = ((const float4*)bias)[2 * f];
    float4 bb1 = ((const float4*)bias)[2 * f + 1];
    float v[8];
    v[0] = fmaxf(di * (a0 + bfl(hs.x)) + bb0.x, 0.f);
    v[1] = fmaxf(di * (a1 + bfh(hs.x)) + bb0.y, 0.f);
    v[2] = fmaxf(di * (a2 + bfl(hs.y)) + bb0.z, 0.f);
    v[3] = fmaxf(di * (a3 + bfh(hs.y)) + bb0.w, 0.f);
    v[4] = fmaxf(di * (a4 + bfl(hs.z)) + bb1.x, 0.f);
    v[5] = fmaxf(di * (a5 + bfh(hs.z)) + bb1.y, 0.f);
    v[6] = fmaxf(di * (a6 + bfl(hs.w)) + bb1.z, 0.f);
    v[7] = fmaxf(di * (a7 + bfh(hs.w)) + bb1.w, 0.f);

    // y[8f..8f+7] = sum_k h[k] * W[k][8f..8f+7]; h[8c+j] lives in lane (ns*8+c).v[j]
    float y0 = 0.f, y1 = 0.f, y2 = 0.f, y3 = 0.f;
    float y4 = 0.f, y5 = 0.f, y6 = 0.f, y7 = 0.f;
    int pb = (lane & 56) << 2;        // byte addr of this node's lane-group base
#pragma unroll
    for (int c = 0; c < 8; ++c) {
        int ad = pb + 4 * c;
#pragma unroll
        for (int j = 0; j < 8; ++j) {
            float hk = __int_as_float(
                __builtin_amdgcn_ds_bpermute(ad, __float_as_int(v[j])));
            float4 w0 = sW[(8 * c + j) * 16 + 2 * f];
            float4 w1 = sW[(8 * c + j) * 16 + 2 * f + 1];
            y0 += hk * w0.x; y1 += hk * w0.y; y2 += hk * w0.z; y3 += hk * w0.w;
            y4 += hk * w1.x; y5 += hk * w1.y; y6 += hk * w1.z; y7 += hk * w1.w;
        }
    }

    uint4 u;
    u.x = pack2bf(y0 * di, y1 * di);
    u.y = pack2bf(y2 * di, y3 * di);
    u.z = pack2bf(y4 * di, y5 * di);
    u.w = pack2bf(y6 * di, y7 * di);
    ((uint4*)Hout)[(size_t)node * 8 + f] = u;
}

// ---------------- layer-3 gather fused with pooling dot: writes pdot[node] ----------------
__global__ __launch_bounds__(256) void gather_pool(const int* __restrict__ rbeg,
                                                   const int* __restrict__ rend,
                                                   const int* __restrict__ eidx,
                                                   const float* __restrict__ dinv,
                                                   const unsigned short* __restrict__ Hn,
                                                   const float* __restrict__ b,
                                                   const float* __restrict__ Wl,
                                                   float* __restrict__ pdot, int n) {
    int wv = (blockIdx.x * blockDim.x + threadIdx.x) >> 6;
    int lane = threadIdx.x & 63;
    int ns = lane >> 3, f = lane & 7;
    int node = wv * 8 + ns;
    bool valid = node < n;
    int beg = valid ? rbeg[node] : 0;
    int end = valid ? rend[node] : 0;
    const char* Hb = (const char*)Hn;

    float a0 = 0.f, a1 = 0.f, a2 = 0.f, a3 = 0.f;
    float a4 = 0.f, a5 = 0.f, a6 = 0.f, a7 = 0.f;
    for (int k = beg; k < end; k += 4) {
        int4 o = *(const int4*)(eidx + k);
        uint4 p = *(const uint4*)(Hb + o.x + f * 16);
        uint4 q = *(const uint4*)(Hb + o.y + f * 16);
        uint4 r = *(const uint4*)(Hb + o.z + f * 16);
        uint4 w = *(const uint4*)(Hb + o.w + f * 16);
        a0 += (bfl(p.x) + bfl(q.x)) + (bfl(r.x) + bfl(w.x));
        a1 += (bfh(p.x) + bfh(q.x)) + (bfh(r.x) + bfh(w.x));
        a2 += (bfl(p.y) + bfl(q.y)) + (bfl(r.y) + bfl(w.y));
        a3 += (bfh(p.y) + bfh(q.y)) + (bfh(r.y) + bfh(w.y));
        a4 += (bfl(p.z) + bfl(q.z)) + (bfl(r.z) + bfl(w.z));
        a5 += (bfh(p.z) + bfh(q.z)) + (bfh(r.z) + bfh(w.z));
        a6 += (bfl(p.w) + bfl(q.w)) + (bfl(r.w) + bfl(w.w));
        a7 += (bfh(p.w) + bfh(q.w)) + (bfh(r.w) + bfh(w.w));
    }

    float di = valid ? dinv[node] : 0.f;
    uint4 hs = valid ? *(const uint4*)(Hb + (size_t)node * 128 + f * 16)
                     : make_uint4(0u, 0u, 0u, 0u);
    float4 b0 = ((const float4*)b)[2 * f];
    float4 b1 = ((const float4*)b)[2 * f + 1];
    float4 w0 = ((const float4*)Wl)[2 * f];
    float4 w1 = ((const float4*)Wl)[2 * f + 1];
    float d = 0.f;
    d += fmaxf(di * (a0 + bfl(hs.x)) + b0.x, 0.f) * w0.x;
    d += fmaxf(di * (a1 + bfh(hs.x)) + b0.y, 0.f) * w0.y;
    d += fmaxf(di * (a2 + bfl(hs.y)) + b0.z, 0.f) * w0.z;
    d += fmaxf(di * (a3 + bfh(hs.y)) + b0.w, 0.f) * w0.w;
    d += fmaxf(di * (a4 + bfl(hs.z)) + b1.x, 0.f) * w1.x;
    d += fmaxf(di * (a5 + bfh(hs.z)) + b1.y, 0.f) * w1.y;
    d += fmaxf(di * (a6 + bfl(hs.w)) + b1.z, 0.f) * w1.z;
    d += fmaxf(di * (a7 + bfh(hs.w)) + b1.w, 0.f) * w1.w;
#pragma unroll
    for (int m = 1; m <= 4; m <<= 1) d += __shfl_xor(d, m);
    if (valid && f == 0) pdot[node] = d;
}

// ---------------- final: per-graph mean of pdot + bias ----------------
__global__ __launch_bounds__(64) void final_out(const float* __restrict__ pdot,
                                                const int* __restrict__ batch,
                                                const float* __restrict__ bl,
                                                float* __restrict__ out) {
    int g = blockIdx.x;
    __shared__ int slo, shi;
    int lane = threadIdx.x;
    if (lane == 0) {
        int a = 0, b = N_NODES;
        while (a < b) { int m = (a + b) >> 1; if (batch[m] < g) a = m + 1; else b = m; }
        slo = a;
        b = N_NODES;
        while (a < b) { int m = (a + b) >> 1; if (batch[m] < g + 1) a = m + 1; else b = m; }
        shi = a;
    }
    __syncthreads();
    int lo = slo, hi = shi;
    float acc = 0.f;
    for (int i = lo + lane; i < hi; i += 64) acc += pdot[i];
#pragma unroll
    for (int off = 32; off > 0; off >>= 1) acc += __shfl_down(acc, off);
    if (lane == 0) {
        float cnt = (float)(hi - lo);
        out[g] = acc / fmaxf(cnt, 1.0f) + bl[0];
    }
}

extern "C" void kernel_launch(void* const* d_in, const int* in_sizes, int n_in,
                              void* d_out, int out_size, void* d_ws, size_t ws_size,
                              hipStream_t stream) {
    const float* x     = (const float*)d_in[0];
    const int*   src   = (const int*)d_in[1];
    const int*   dst   = (const int*)d_in[2];
    const int*   batch = (const int*)d_in[3];
    const float* W1 = (const float*)d_in[4];  const float* b1 = (const float*)d_in[5];
    const float* W2 = (const float*)d_in[6];  const float* b2 = (const float*)d_in[7];
    const float* W3 = (const float*)d_in[8];  const float* b3 = (const float*)d_in[9];
    const float* Wl = (const float*)d_in[10]; const float* bl = (const float*)d_in[11];
    float* out = (float*)d_out;

    char* ws = (char*)d_ws;
    unsigned short* Abf = (unsigned short*)ws;                       // (N+1)*F bf16 (Hn buf A + zero row)
    unsigned short* Bbf = Abf + (size_t)(N_NODES + 1) * F;           // (N+1)*F bf16 (Hn buf B + zero row)
    float* dinv    = (float*)(Bbf + (size_t)(N_NODES + 1) * F);      // N
    float* pdot    = dinv + N_NODES;                                 // N
    int*   rbeg    = (int*)(pdot + N_NODES);                         // N
    int*   rend    = rbeg + N_NODES;                                 // N
    int*   bcur    = rend + N_NODES;                                 // NBUCK
    unsigned int* bpair = (unsigned int*)(bcur + NBUCK);             // NBUCK*CAP
    int*   eidx    = (int*)(bpair + (size_t)NBUCK * CAP);            // NBUCK*CAP

    const int GEMM_GRID   = (N_NODES + 127) / 128;                   // 391
    const int GATHER_GRID = (N_NODES + 31) / 32;                     // 1563 (8 nodes/wave)

    // ---- preprocessing: padded-CSR build (rbeg/rend, eidx, dinv, zero rows) ----
    hipMemsetAsync(bcur, 0, NBUCK * sizeof(int), stream);
    partition_edges<<<P3_GRID, 256, 0, stream>>>(src, dst, bcur, bpair);
    bucket_sort<<<NBUCK, 256, 0, stream>>>(bpair, bcur, eidx, rbeg, rend, dinv, Abf, Bbf);

    // ---- layer 1 GEMM (f32 input) ----
    gemm64_f32<<<GEMM_GRID, 256, 0, stream>>>(x, W1, dinv, Abf, N_NODES);

    // ---- layer 1 gather fused with layer-2 GEMM: A -> B ----
    gather_gemm<<<GATHER_GRID, 256, 0, stream>>>(rbeg, rend, eidx, dinv, Abf, b1, W2, Bbf, N_NODES);

    // ---- layer 2 gather fused with layer-3 GEMM: B -> A ----
    gather_gemm<<<GATHER_GRID, 256, 0, stream>>>(rbeg, rend, eidx, dinv, Bbf, b2, W3, Abf, N_NODES);

    // ---- layer 3 gather fused with pooling dot: A -> pdot ----
    gather_pool<<<GATHER_GRID, 256, 0, stream>>>(rbeg, rend, eidx, dinv, Abf, b3, Wl, pdot, N_NODES);

    // ---- final: per-graph mean + bias ----
    final_out<<<N_GRAPHS, 64, 0, stream>>>(pdot, batch, bl, out);
}

// Round 2
// 193.240 us; speedup vs baseline: 1.0716x; 1.0125x over previous
//
#include <hip/hip_runtime.h>

#define N_NODES 50000
#define N_EDGES 800000
#define N_GRAPHS 256
#define F 64
#define NBUCK 196          // ceil(50000/256) coarse buckets (dst>>8)
#define CAP 5120           // per-bucket capacity incl. 4-align padding
#define P3_TILE 2048
#define P3_GRID ((N_EDGES + P3_TILE - 1) / P3_TILE)
#define BCAP 6144
#define ZOFF (N_NODES * 128) // byte offset of the zero row in Hn

// ---- bf16 helpers (RTN), all math stays f32 ----
__device__ __forceinline__ unsigned short f2bf(float f) {
    union { float f; unsigned u; } c; c.f = f;
    unsigned u = c.u + 0x7FFFu + ((c.u >> 16) & 1u);
    return (unsigned short)(u >> 16);
}
__device__ __forceinline__ unsigned pack2bf(float lo, float hi) {
    return (unsigned)f2bf(lo) | ((unsigned)f2bf(hi) << 16);
}
__device__ __forceinline__ float bfl(unsigned u) {
    union { unsigned u; float f; } c; c.u = u << 16; return c.f;
}
__device__ __forceinline__ float bfh(unsigned u) {
    union { unsigned u; float f; } c; c.u = u & 0xFFFF0000u; return c.f;
}

// ---- depth-2 software-pipelined gather over one node's padded edge run ----
// Issues eidx[k+8] + row loads for k+4 BEFORE accumulating rows of k, so the
// eidx->addr->row dependent chain spans iterations instead of serializing each
// one. Tail prefetches use clamped (valid) indices; results are discarded.
__device__ __forceinline__ void gather_run(const int* __restrict__ eidx,
                                           const char* __restrict__ Hb,
                                           int beg, int end, int fo, float* a) {
#pragma unroll
    for (int i = 0; i < 8; ++i) a[i] = 0.f;
    int kb = (beg < end) ? beg : 0;          // always-valid descriptor slot
    int4 oc = *(const int4*)(eidx + kb);
    int k1 = beg + 4;
    int k1c = (k1 < end) ? k1 : kb;
    int4 on = *(const int4*)(eidx + k1c);
    uint4 pc = *(const uint4*)(Hb + oc.x + fo);
    uint4 qc = *(const uint4*)(Hb + oc.y + fo);
    uint4 rc = *(const uint4*)(Hb + oc.z + fo);
    uint4 wc = *(const uint4*)(Hb + oc.w + fo);
    for (int k = beg; k < end; k += 4) {
        int k2 = k + 8;
        int k2c = (k2 < end) ? k2 : kb;
        int4 of = *(const int4*)(eidx + k2c);
        uint4 pn = *(const uint4*)(Hb + on.x + fo);
        uint4 qn = *(const uint4*)(Hb + on.y + fo);
        uint4 rn = *(const uint4*)(Hb + on.z + fo);
        uint4 wn = *(const uint4*)(Hb + on.w + fo);
        a[0] += (bfl(pc.x) + bfl(qc.x)) + (bfl(rc.x) + bfl(wc.x));
        a[1] += (bfh(pc.x) + bfh(qc.x)) + (bfh(rc.x) + bfh(wc.x));
        a[2] += (bfl(pc.y) + bfl(qc.y)) + (bfl(rc.y) + bfl(wc.y));
        a[3] += (bfh(pc.y) + bfh(qc.y)) + (bfh(rc.y) + bfh(wc.y));
        a[4] += (bfl(pc.z) + bfl(qc.z)) + (bfl(rc.z) + bfl(wc.z));
        a[5] += (bfh(pc.z) + bfh(qc.z)) + (bfh(rc.z) + bfh(wc.z));
        a[6] += (bfl(pc.w) + bfl(qc.w)) + (bfl(rc.w) + bfl(wc.w));
        a[7] += (bfh(pc.w) + bfh(qc.w)) + (bfh(rc.w) + bfh(wc.w));
        oc = on; on = of;
        pc = pn; qc = qn; rc = rn; wc = wn;
    }
}

// ---------------- P1: partition edges into fixed-capacity buckets ----------------
__global__ __launch_bounds__(256) void partition_edges(const int* __restrict__ src,
                                                       const int* __restrict__ dst,
                                                       int* __restrict__ bcur,
                                                       unsigned int* __restrict__ bpair) {
    __shared__ int bh[NBUCK], bloc[NBUCK], bpos[NBUCK];
    int t = threadIdx.x;
    int lo = blockIdx.x * P3_TILE;
    int hi = min(lo + P3_TILE, N_EDGES);
    for (int i = t; i < NBUCK; i += 256) { bh[i] = 0; bpos[i] = 0; }
    __syncthreads();
    for (int e = lo + t; e < hi; e += 256) atomicAdd(&bh[dst[e] >> 8], 1);
    __syncthreads();
    for (int i = t; i < NBUCK; i += 256)
        bloc[i] = bh[i] ? atomicAdd(&bcur[i], bh[i]) : 0;
    __syncthreads();
    for (int e = lo + t; e < hi; e += 256) {
        int d = dst[e];
        int b = d >> 8;
        int r = atomicAdd(&bpos[b], 1);
        bpair[(size_t)b * CAP + bloc[b] + r] = ((unsigned)src[e] << 8) | (unsigned)(d & 255);
    }
}

// ---------------- P2: per-bucket counting sort -> 4-aligned padded CSR ----------------
__global__ __launch_bounds__(256) void bucket_sort(const unsigned int* __restrict__ bpair,
                                                   const int* __restrict__ bcur,
                                                   int* __restrict__ eidx,
                                                   int* __restrict__ rbeg,
                                                   int* __restrict__ rend,
                                                   float* __restrict__ dinv,
                                                   unsigned short* __restrict__ Abf,
                                                   unsigned short* __restrict__ Bbf) {
    __shared__ int cnt[256], s[256], pos[256];
    __shared__ int lout[BCAP];
    int b = blockIdx.x, t = threadIdx.x;
    int base = b * CAP;
    int sz = bcur[b];

    if (b == 0 && t < 8) {
        ((uint4*)Abf)[(size_t)N_NODES * 8 + t] = make_uint4(0u, 0u, 0u, 0u);
        ((uint4*)Bbf)[(size_t)N_NODES * 8 + t] = make_uint4(0u, 0u, 0u, 0u);
    }

    cnt[t] = 0;
    __syncthreads();
    for (int i = t; i < sz; i += 256) atomicAdd(&cnt[bpair[base + i] & 255], 1);
    __syncthreads();
    int v = cnt[t];
    int pv = (v + 3) & ~3;          // padded to multiple of 4
    s[t] = pv;
    __syncthreads();
    for (int off = 1; off < 256; off <<= 1) {
        int u = (t >= off) ? s[t - off] : 0;
        __syncthreads();
        s[t] += u;
        __syncthreads();
    }
    int excl = s[t] - pv;            // padded exclusive prefix
    pos[t] = excl;
    int node = b * 256 + t;
    if (node < N_NODES) {
        rbeg[node] = base + excl;
        rend[node] = base + excl + pv;                 // padded end (loop bound)
        dinv[node] = 1.0f / sqrtf((float)v + 1.0f);    // actual degree +1 self-loop
    }
    int padtot = s[255];             // total padded size of this bucket
    __syncthreads();

    // scatter actual edges
    for (int i = t; i < sz; i += 256) {
        unsigned p = bpair[base + i];
        int r = atomicAdd(&pos[p & 255], 1);
        lout[r] = (int)((p >> 8) << 7);   // src byte offset (src*128, bf16 row)
    }
    __syncthreads();
    // fill pad slots with zero-row sentinel (each thread pads its own node run)
    for (int j = v; j < pv; j++) lout[excl + j] = ZOFF;
    __syncthreads();
    for (int i = t; i < padtot; i += 256) eidx[base + i] = lout[i];
}

// ---------------- GEMM + dinv fold: Hn[i,:] = bf16( (X[i,:] @ W) * dinv[i] ) ----------------
// Only used for layer 1 (f32 input x); layers 2/3 GEMMs are fused into the gathers.
#define XSTRIDE 17
__global__ __launch_bounds__(256) void gemm64_f32(const float* __restrict__ X,
                                                  const float* __restrict__ W,
                                                  const float* __restrict__ dinv,
                                                  unsigned short* __restrict__ Hn, int n) {
    __shared__ float4 sW[64 * 16];
    __shared__ float4 sX[128 * XSTRIDE];
    int tid = threadIdx.x;
    int base = blockIdx.x * 128;

    const float4* W4 = (const float4*)W;
    for (int i = tid; i < 64 * 16; i += 256) sW[i] = W4[i];
    {
        const float4* X4 = (const float4*)X;
        for (int i = tid; i < 128 * 16; i += 256) {
            int r = i >> 4, kg = i & 15;
            int node = base + r;
            sX[r * XSTRIDE + kg] = (node < n) ? X4[(size_t)node * 16 + kg]
                                              : make_float4(0.f, 0.f, 0.f, 0.f);
        }
    }
    __syncthreads();

    int fg = tid & 15;
    int ng = tid >> 4;
    float4 acc[8];
#pragma unroll
    for (int ii = 0; ii < 8; ii++) acc[ii] = make_float4(0.f, 0.f, 0.f, 0.f);

    for (int kg = 0; kg < 16; kg++) {
        float4 xv[8];
#pragma unroll
        for (int ii = 0; ii < 8; ii++) xv[ii] = sX[(ng + 16 * ii) * XSTRIDE + kg];
#pragma unroll
        for (int kk = 0; kk < 4; kk++) {
            float4 wv = sW[(4 * kg + kk) * 16 + fg];
#pragma unroll
            for (int ii = 0; ii < 8; ii++) {
                float xs = (kk == 0) ? xv[ii].x : (kk == 1) ? xv[ii].y
                         : (kk == 2) ? xv[ii].z : xv[ii].w;
                acc[ii].x += wv.x * xs;
                acc[ii].y += wv.y * xs;
                acc[ii].z += wv.z * xs;
                acc[ii].w += wv.w * xs;
            }
        }
    }

    ushort4* H4 = (ushort4*)Hn;
#pragma unroll
    for (int ii = 0; ii < 8; ii++) {
        int node = base + ng + 16 * ii;
        if (node < n) {
            float d = dinv[node];
            float4 o = acc[ii];
            ushort4 u;
            u.x = f2bf(o.x * d); u.y = f2bf(o.y * d);
            u.z = f2bf(o.z * d); u.w = f2bf(o.w * d);
            H4[(size_t)node * 16 + fg] = u;
        }
    }
}

// ---------------- fused gather + next-layer GEMM (layers 1->2, 2->3) ----------------
__global__ __launch_bounds__(256) void gather_gemm(const int* __restrict__ rbeg,
                                                   const int* __restrict__ rend,
                                                   const int* __restrict__ eidx,
                                                   const float* __restrict__ dinv,
                                                   const unsigned short* __restrict__ Hin,
                                                   const float* __restrict__ bias,
                                                   const float* __restrict__ W,
                                                   unsigned short* __restrict__ Hout, int n) {
    __shared__ float4 sW[64 * 16];
    const float4* W4 = (const float4*)W;
    for (int i = threadIdx.x; i < 64 * 16; i += 256) sW[i] = W4[i];
    __syncthreads();

    int wv = (blockIdx.x * blockDim.x + threadIdx.x) >> 6;
    if (wv * 8 >= n) return;          // whole-wave guard (n % 8 == 0)
    int lane = threadIdx.x & 63;
    int ns = lane >> 3, f = lane & 7;
    int node = wv * 8 + ns;
    int beg = rbeg[node];
    int end = rend[node];
    const char* Hb = (const char*)Hin;

    // hoist independent epilogue loads above the latency-bound loop
    float di = dinv[node];
    uint4 hs = *(const uint4*)(Hb + (size_t)node * 128 + f * 16);
    float4 bb0 = ((const float4*)bias)[2 * f];
    float4 bb1 = ((const float4*)bias)[2 * f + 1];

    float a[8];
    gather_run(eidx, Hb, beg, end, f * 16, a);

    float v[8];
    v[0] = fmaxf(di * (a[0] + bfl(hs.x)) + bb0.x, 0.f);
    v[1] = fmaxf(di * (a[1] + bfh(hs.x)) + bb0.y, 0.f);
    v[2] = fmaxf(di * (a[2] + bfl(hs.y)) + bb0.z, 0.f);
    v[3] = fmaxf(di * (a[3] + bfh(hs.y)) + bb0.w, 0.f);
    v[4] = fmaxf(di * (a[4] + bfl(hs.z)) + bb1.x, 0.f);
    v[5] = fmaxf(di * (a[5] + bfh(hs.z)) + bb1.y, 0.f);
    v[6] = fmaxf(di * (a[6] + bfl(hs.w)) + bb1.z, 0.f);
    v[7] = fmaxf(di * (a[7] + bfh(hs.w)) + bb1.w, 0.f);

    // y[8f..8f+7] = sum_k h[k] * W[k][8f..8f+7]; h[8c+j] lives in lane (ns*8+c).v[j]
    float y0 = 0.f, y1 = 0.f, y2 = 0.f, y3 = 0.f;
    float y4 = 0.f, y5 = 0.f, y6 = 0.f, y7 = 0.f;
    int pb = (lane & 56) << 2;        // byte addr of this node's lane-group base
#pragma unroll
    for (int c = 0; c < 8; ++c) {
        int ad = pb + 4 * c;
#pragma unroll
        for (int j = 0; j < 8; ++j) {
            float hk = __int_as_float(
                __builtin_amdgcn_ds_bpermute(ad, __float_as_int(v[j])));
            float4 w0 = sW[(8 * c + j) * 16 + 2 * f];
            float4 w1 = sW[(8 * c + j) * 16 + 2 * f + 1];
            y0 += hk * w0.x; y1 += hk * w0.y; y2 += hk * w0.z; y3 += hk * w0.w;
            y4 += hk * w1.x; y5 += hk * w1.y; y6 += hk * w1.z; y7 += hk * w1.w;
        }
    }

    uint4 u;
    u.x = pack2bf(y0 * di, y1 * di);
    u.y = pack2bf(y2 * di, y3 * di);
    u.z = pack2bf(y4 * di, y5 * di);
    u.w = pack2bf(y6 * di, y7 * di);
    ((uint4*)Hout)[(size_t)node * 8 + f] = u;
}

// ---------------- layer-3 gather fused with pooling dot: writes pdot[node] ----------------
__global__ __launch_bounds__(256) void gather_pool(const int* __restrict__ rbeg,
                                                   const int* __restrict__ rend,
                                                   const int* __restrict__ eidx,
                                                   const float* __restrict__ dinv,
                                                   const unsigned short* __restrict__ Hn,
                                                   const float* __restrict__ b,
                                                   const float* __restrict__ Wl,
                                                   float* __restrict__ pdot, int n) {
    int wv = (blockIdx.x * blockDim.x + threadIdx.x) >> 6;
    int lane = threadIdx.x & 63;
    int ns = lane >> 3, f = lane & 7;
    int node = wv * 8 + ns;
    bool valid = node < n;
    int nodec = valid ? node : 0;
    int beg = valid ? rbeg[node] : 0;
    int end = valid ? rend[node] : 0;
    const char* Hb = (const char*)Hn;

    // hoist independent epilogue loads above the loop (clamped addresses)
    float di = dinv[nodec];
    uint4 hs = *(const uint4*)(Hb + (size_t)nodec * 128 + f * 16);
    float4 b0 = ((const float4*)b)[2 * f];
    float4 b1 = ((const float4*)b)[2 * f + 1];
    float4 w0 = ((const float4*)Wl)[2 * f];
    float4 w1 = ((const float4*)Wl)[2 * f + 1];

    float a[8];
    gather_run(eidx, Hb, beg, end, f * 16, a);

    float d = 0.f;
    d += fmaxf(di * (a[0] + bfl(hs.x)) + b0.x, 0.f) * w0.x;
    d += fmaxf(di * (a[1] + bfh(hs.x)) + b0.y, 0.f) * w0.y;
    d += fmaxf(di * (a[2] + bfl(hs.y)) + b0.z, 0.f) * w0.z;
    d += fmaxf(di * (a[3] + bfh(hs.y)) + b0.w, 0.f) * w0.w;
    d += fmaxf(di * (a[4] + bfl(hs.z)) + b1.x, 0.f) * w1.x;
    d += fmaxf(di * (a[5] + bfh(hs.z)) + b1.y, 0.f) * w1.y;
    d += fmaxf(di * (a[6] + bfl(hs.w)) + b1.z, 0.f) * w1.z;
    d += fmaxf(di * (a[7] + bfh(hs.w)) + b1.w, 0.f) * w1.w;
#pragma unroll
    for (int m = 1; m <= 4; m <<= 1) d += __shfl_xor(d, m);
    if (valid && f == 0) pdot[node] = d;
}

// ---------------- final: per-graph mean of pdot + bias ----------------
__global__ __launch_bounds__(64) void final_out(const float* __restrict__ pdot,
                                                const int* __restrict__ batch,
                                                const float* __restrict__ bl,
                                                float* __restrict__ out) {
    int g = blockIdx.x;
    __shared__ int slo, shi;
    int lane = threadIdx.x;
    if (lane == 0) {
        int a = 0, b = N_NODES;
        while (a < b) { int m = (a + b) >> 1; if (batch[m] < g) a = m + 1; else b = m; }
        slo = a;
        b = N_NODES;
        while (a < b) { int m = (a + b) >> 1; if (batch[m] < g + 1) a = m + 1; else b = m; }
        shi = a;
    }
    __syncthreads();
    int lo = slo, hi = shi;
    float acc = 0.f;
    for (int i = lo + lane; i < hi; i += 64) acc += pdot[i];
#pragma unroll
    for (int off = 32; off > 0; off >>= 1) acc += __shfl_down(acc, off);
    if (lane == 0) {
        float cnt = (float)(hi - lo);
        out[g] = acc / fmaxf(cnt, 1.0f) + bl[0];
    }
}

extern "C" void kernel_launch(void* const* d_in, const int* in_sizes, int n_in,
                              void* d_out, int out_size, void* d_ws, size_t ws_size,
                              hipStream_t stream) {
    const float* x     = (const float*)d_in[0];
    const int*   src   = (const int*)d_in[1];
    const int*   dst   = (const int*)d_in[2];
    const int*   batch = (const int*)d_in[3];
    const float* W1 = (const float*)d_in[4];  const float* b1 = (const float*)d_in[5];
    const float* W2 = (const float*)d_in[6];  const float* b2 = (const float*)d_in[7];
    const float* W3 = (const float*)d_in[8];  const float* b3 = (const float*)d_in[9];
    const float* Wl = (const float*)d_in[10]; const float* bl = (const float*)d_in[11];
    float* out = (float*)d_out;

    char* ws = (char*)d_ws;
    unsigned short* Abf = (unsigned short*)ws;                       // (N+1)*F bf16 (Hn buf A + zero row)
    unsigned short* Bbf = Abf + (size_t)(N_NODES + 1) * F;           // (N+1)*F bf16 (Hn buf B + zero row)
    float* dinv    = (float*)(Bbf + (size_t)(N_NODES + 1) * F);      // N
    float* pdot    = dinv + N_NODES;                                 // N
    int*   rbeg    = (int*)(pdot + N_NODES);                         // N
    int*   rend    = rbeg + N_NODES;                                 // N
    int*   bcur    = rend + N_NODES;                                 // NBUCK
    unsigned int* bpair = (unsigned int*)(bcur + NBUCK);             // NBUCK*CAP
    int*   eidx    = (int*)(bpair + (size_t)NBUCK * CAP);            // NBUCK*CAP

    const int GEMM_GRID   = (N_NODES + 127) / 128;                   // 391
    const int GATHER_GRID = (N_NODES + 31) / 32;                     // 1563 (8 nodes/wave)

    // ---- preprocessing: padded-CSR build (rbeg/rend, eidx, dinv, zero rows) ----
    hipMemsetAsync(bcur, 0, NBUCK * sizeof(int), stream);
    partition_edges<<<P3_GRID, 256, 0, stream>>>(src, dst, bcur, bpair);
    bucket_sort<<<NBUCK, 256, 0, stream>>>(bpair, bcur, eidx, rbeg, rend, dinv, Abf, Bbf);

    // ---- layer 1 GEMM (f32 input) ----
    gemm64_f32<<<GEMM_GRID, 256, 0, stream>>>(x, W1, dinv, Abf, N_NODES);

    // ---- layer 1 gather fused with layer-2 GEMM: A -> B ----
    gather_gemm<<<GATHER_GRID, 256, 0, stream>>>(rbeg, rend, eidx, dinv, Abf, b1, W2, Bbf, N_NODES);

    // ---- layer 2 gather fused with layer-3 GEMM: B -> A ----
    gather_gemm<<<GATHER_GRID, 256, 0, stream>>>(rbeg, rend, eidx, dinv, Bbf, b2, W3, Abf, N_NODES);

    // ---- layer 3 gather fused with pooling dot: A -> pdot ----
    gather_pool<<<GATHER_GRID, 256, 0, stream>>>(rbeg, rend, eidx, dinv, Abf, b3, Wl, pdot, N_NODES);

    // ---- final: per-graph mean + bias ----
    final_out<<<N_GRAPHS, 64, 0, stream>>>(pdot, batch, bl, out);
}